// Round 2
// baseline (220.890 us; speedup 1.0000x reference)
//
#include <hip/hip_runtime.h>

#define N_ROWS 8192
#define DIM    512
#define BK     64

typedef __attribute__((ext_vector_type(8))) short frag_ab;  // 8 bf16 (4 VGPRs)
typedef __attribute__((ext_vector_type(4))) float frag_cd;  // 4 fp32 acc

__device__ __forceinline__ unsigned short f2bf(float f) {
    unsigned u = __float_as_uint(f);
    u += 0x7FFFu + ((u >> 16) & 1u);   // RNE
    return (unsigned short)(u >> 16);
}
__device__ __forceinline__ unsigned pack2(float a, float b) {
    return (unsigned)f2bf(a) | ((unsigned)f2bf(b) << 16);
}
// order-preserving f32 -> u32 key (monotone), so atomicMax(uint) == float max
__device__ __forceinline__ unsigned enc_f32(float f) {
    unsigned u = __float_as_uint(f);
    return (u & 0x80000000u) ? ~u : (u | 0x80000000u);
}
__device__ __forceinline__ float dec_f32(unsigned k) {
    return __uint_as_float((k & 0x80000000u) ? (k & 0x7FFFFFFFu) : ~k);
}

// ---- kernel 1: fused fp32->bf16 convert + fp32 diag dot + max-key init ----
// One wave per row; reads imgs+caps exactly once (64 MB), writes bf16 (32 MB).
__global__ __launch_bounds__(256) void k_prep(const float* __restrict__ imgs,
                                              const float* __restrict__ caps,
                                              uint4* __restrict__ bimgs,
                                              uint4* __restrict__ bcaps,
                                              float* __restrict__ diag,
                                              unsigned* __restrict__ rowmax,
                                              unsigned* __restrict__ colmax) {
    const int w = threadIdx.x >> 6, lane = threadIdx.x & 63;
    const int row = blockIdx.x * 4 + w;
    const float4* ip = (const float4*)(imgs + (size_t)row * DIM);
    const float4* cp = (const float4*)(caps + (size_t)row * DIM);
    float4 a0 = ip[2 * lane], a1 = ip[2 * lane + 1];
    float4 b0 = cp[2 * lane], b1 = cp[2 * lane + 1];
    uint4 oa, ob;
    oa.x = pack2(a0.x, a0.y); oa.y = pack2(a0.z, a0.w);
    oa.z = pack2(a1.x, a1.y); oa.w = pack2(a1.z, a1.w);
    ob.x = pack2(b0.x, b0.y); ob.y = pack2(b0.z, b0.w);
    ob.z = pack2(b1.x, b1.y); ob.w = pack2(b1.z, b1.w);
    bimgs[row * 64 + lane] = oa;
    bcaps[row * 64 + lane] = ob;
    float s = a0.x * b0.x + a0.y * b0.y + a0.z * b0.z + a0.w * b0.w
            + a1.x * b1.x + a1.y * b1.y + a1.z * b1.z + a1.w * b1.w;
    #pragma unroll
    for (int m = 1; m < 64; m <<= 1) s += __shfl_xor(s, m, 64);
    if (lane == 0) { diag[row] = s; rowmax[row] = 0u; colmax[row] = 0u; }
}

// ---- kernel 2: fused bf16 NT-GEMM + diag flip + row/col max ----
// 128x128 tile, BK=64 (8 K-iters), 4 waves of 64x64.
// LDS rows are 128 B (=32 banks) -> XOR-swizzle: physical colgroup = logical ^ (row&7).
// Swizzle is applied on the global_load_lds SOURCE address (LDS dest is fixed
// base+lane*16) and symmetrically on the fragment reads -> 2-way conflicts (free).
__global__ __launch_bounds__(256) void k_gemm(const unsigned short* __restrict__ A,
                                              const unsigned short* __restrict__ B,
                                              unsigned* __restrict__ rowmax,
                                              unsigned* __restrict__ colmax) {
    __shared__ unsigned short sA[128 * BK];   // 16 KB
    __shared__ unsigned short sB[128 * BK];   // 16 KB
    const int tid = threadIdx.x;
    const int w = tid >> 6, lane = tid & 63;
    const int i0 = (int)blockIdx.y << 7, j0 = (int)blockIdx.x << 7;
    const int q = lane >> 4, l15 = lane & 15;
    const int wrow = (w >> 1) << 6, wcol = (w & 1) << 6;

    frag_cd acc[4][4] = {};

    // staging: per glds instr one wave covers 8 rows x 64 cols.
    const int srow8 = lane >> 3;                    // 0..7
    const int scol  = ((lane & 7) ^ srow8) << 3;    // swizzled logical col (elems)
    const unsigned short* gA0 = A + (size_t)(i0 + w * 32 + srow8) * DIM + scol;
    const unsigned short* gB0 = B + (size_t)(j0 + w * 32 + srow8) * DIM + scol;
    unsigned short* lA0 = sA + w * 32 * BK + lane * 8;
    unsigned short* lB0 = sB + w * 32 * BK + lane * 8;

    for (int k0 = 0; k0 < DIM; k0 += BK) {
        __syncthreads();  // prior ds_reads retired before LDS overwrite
        #pragma unroll
        for (int j = 0; j < 4; ++j) {
            __builtin_amdgcn_global_load_lds(
                (const __attribute__((address_space(1))) unsigned int*)(gA0 + (size_t)j * 8 * DIM + k0),
                (__attribute__((address_space(3))) unsigned int*)(lA0 + j * 8 * BK), 16, 0, 0);
            __builtin_amdgcn_global_load_lds(
                (const __attribute__((address_space(1))) unsigned int*)(gB0 + (size_t)j * 8 * DIM + k0),
                (__attribute__((address_space(3))) unsigned int*)(lB0 + j * 8 * BK), 16, 0, 0);
        }
        __syncthreads();  // drains vmcnt -> LDS valid

        #pragma unroll
        for (int p = 0; p < 2; ++p) {
            const int cg = ((p << 2) + q) ^ (l15 & 7);  // swizzled colgroup
            frag_ab af[4], bfr[4];
            #pragma unroll
            for (int r = 0; r < 4; ++r)
                af[r] = *(const frag_ab*)(sA + (wrow + (r << 4) + l15) * BK + (cg << 3));
            #pragma unroll
            for (int c = 0; c < 4; ++c)
                bfr[c] = *(const frag_ab*)(sB + (wcol + (c << 4) + l15) * BK + (cg << 3));
            #pragma unroll
            for (int r = 0; r < 4; ++r)
                #pragma unroll
                for (int c = 0; c < 4; ++c)
                    acc[r][c] = __builtin_amdgcn_mfma_f32_16x16x32_bf16(af[r], bfr[c], acc[r][c], 0, 0, 0);
        }
    }

    // ---- epilogue: diagonal flip + row/col max + device atomics ----
    // C/D layout: col = lane&15, row = (lane>>4)*4 + reg  [m89-verified]
    const bool dblk = (i0 == j0);
    #pragma unroll
    for (int r = 0; r < 4; ++r)
        #pragma unroll
        for (int c = 0; c < 4; ++c)
            #pragma unroll
            for (int g = 0; g < 4; ++g) {
                float f = acc[r][c][g];
                if (dblk && (wrow + (r << 4) + (q << 2) + g) == (wcol + (c << 4) + l15))
                    f = -f;   // s[i][i] = -diag
                acc[r][c][g] = f;
            }

    // row maxes: reduce over c (in-reg) then over lane&15 (xor 1,2,4,8)
    #pragma unroll
    for (int r = 0; r < 4; ++r)
        #pragma unroll
        for (int g = 0; g < 4; ++g) {
            float m = fmaxf(fmaxf(acc[r][0][g], acc[r][1][g]),
                            fmaxf(acc[r][2][g], acc[r][3][g]));
            m = fmaxf(m, __shfl_xor(m, 1, 64));
            m = fmaxf(m, __shfl_xor(m, 2, 64));
            m = fmaxf(m, __shfl_xor(m, 4, 64));
            m = fmaxf(m, __shfl_xor(m, 8, 64));
            if (l15 == 0)
                atomicMax(&rowmax[i0 + wrow + (r << 4) + (q << 2) + g], enc_f32(m));
        }
    // col maxes: reduce over r,g (in-reg) then over q (xor 16,32)
    #pragma unroll
    for (int c = 0; c < 4; ++c) {
        float m = acc[0][c][0];
        #pragma unroll
        for (int r = 0; r < 4; ++r)
            #pragma unroll
            for (int g = 0; g < 4; ++g) m = fmaxf(m, acc[r][c][g]);
        m = fmaxf(m, __shfl_xor(m, 16, 64));
        m = fmaxf(m, __shfl_xor(m, 32, 64));
        if (q == 0)
            atomicMax(&colmax[j0 + wcol + (c << 4) + l15], enc_f32(m));
    }
}

// ---- kernel 3: hinge terms + scalar reduce ----
__global__ __launch_bounds__(256) void k_final(const unsigned* __restrict__ rowmax,
                                               const unsigned* __restrict__ colmax,
                                               const float* __restrict__ diag,
                                               float* __restrict__ out) {
    int tid = threadIdx.x;
    float s = 0.f;
    for (int i = tid; i < N_ROWS; i += 256) {
        float d = diag[i];
        s += fmaxf(dec_f32(rowmax[i]) + 0.2f - d, 0.f);  // neg_img
        s += fmaxf(dec_f32(colmax[i]) + 0.2f - d, 0.f);  // neg_cap
    }
    #pragma unroll
    for (int m = 1; m < 64; m <<= 1) s += __shfl_xor(s, m, 64);
    __shared__ float red[4];
    if ((tid & 63) == 0) red[tid >> 6] = s;
    __syncthreads();
    if (tid == 0) out[0] = red[0] + red[1] + red[2] + red[3];
}

extern "C" void kernel_launch(void* const* d_in, const int* in_sizes, int n_in,
                              void* d_out, int out_size, void* d_ws, size_t ws_size,
                              hipStream_t stream) {
    const float* imgs = (const float*)d_in[0];
    const float* caps = (const float*)d_in[1];
    float* out = (float*)d_out;

    char* ws = (char*)d_ws;
    unsigned short* bimgs = (unsigned short*)ws;                       // 8 MB
    unsigned short* bcaps = (unsigned short*)(ws + 8388608);           // 8 MB
    float*    diag   = (float*)   (ws + 16777216);                     // 32 KB
    unsigned* rowmax = (unsigned*)(ws + 16777216 + 32768);             // 32 KB
    unsigned* colmax = (unsigned*)(ws + 16777216 + 65536);             // 32 KB

    k_prep<<<N_ROWS / 4, 256, 0, stream>>>(imgs, caps, (uint4*)bimgs, (uint4*)bcaps,
                                           diag, rowmax, colmax);
    k_gemm<<<dim3(64, 64), 256, 0, stream>>>(bimgs, bcaps, rowmax, colmax);
    k_final<<<1, 256, 0, stream>>>(rowmax, colmax, diag, out);
}